// Round 4
// baseline (314.857 us; speedup 1.0000x reference)
//
#include <hip/hip_runtime.h>

#define H 4
#define C 128
#define FOUT 512

typedef __attribute__((ext_vector_type(8))) short s16x8;
typedef __attribute__((ext_vector_type(4))) float f32x4;

__device__ __forceinline__ unsigned int f2bf_bits(float f) {
    unsigned int u = __float_as_uint(f);
    u += 0x7fffu + ((u >> 16) & 1u);
    return u >> 16;
}
__device__ __forceinline__ float bflo(unsigned int u) { return __uint_as_float(u << 16); }
__device__ __forceinline__ float bfhi(unsigned int u) { return __uint_as_float(u & 0xffff0000u); }
__device__ __forceinline__ float leaky(float x) { return (x >= 0.f) ? x : 0.2f * x; }

// ---------------- CSR build ----------------
__global__ void zero_i32(int* __restrict__ p, int n) {
    int i = blockIdx.x * blockDim.x + threadIdx.x;
    if (i < n) p[i] = 0;
}

__global__ void hist_kernel(const int* __restrict__ ei, int E, int N, int* __restrict__ counts) {
    int e = blockIdx.x * blockDim.x + threadIdx.x;
    int M = E + N;
    if (e >= M) return;
    int d = (e < E) ? ei[E + e] : (e - E);
    atomicAdd(&counts[d], 1);
}

__global__ __launch_bounds__(256) void scan_kernel(const int* __restrict__ counts,
                                                   int* __restrict__ row_off,
                                                   int* __restrict__ cursor, int N) {
    __shared__ int part[256];
    int t = threadIdx.x;
    int chunk = (N + 255) >> 8;
    int b = t * chunk; if (b > N) b = N;
    int e = b + chunk; if (e > N) e = N;
    int s = 0;
    for (int i = b; i < e; ++i) s += counts[i];
    part[t] = s;
    __syncthreads();
    for (int off = 1; off < 256; off <<= 1) {
        int v = (t >= off) ? part[t - off] : 0;
        __syncthreads();
        part[t] += v;
        __syncthreads();
    }
    int run = (t == 0) ? 0 : part[t - 1];
    for (int i = b; i < e; ++i) { row_off[i] = run; cursor[i] = run; run += counts[i]; }
    if (t == 255) row_off[N] = part[255];
}

__global__ void scatter_kernel(const int* __restrict__ ei, int E, int N,
                               int* __restrict__ cursor, int* __restrict__ csr_src,
                               int* __restrict__ csr_dst) {
    int e = blockIdx.x * blockDim.x + threadIdx.x;
    int M = E + N;
    if (e >= M) return;
    int s = (e < E) ? ei[e] : (e - E);
    int d = (e < E) ? ei[E + e] : (e - E);
    int pos = atomicAdd(&cursor[d], 1);
    csr_src[pos] = s;
    csr_dst[pos] = d;
}

// ---------------- input conversions ----------------
__global__ void convert_x(const float* __restrict__ x, unsigned short* __restrict__ xA,
                          unsigned short* __restrict__ featsbf, int N, int Npad) {
    int i = blockIdx.x * blockDim.x + threadIdx.x;  // one 4-channel group per thread
    int total = Npad * (C / 4);
    if (i >= total) return;
    int row = i >> 5;
    int c4 = (i & 31) * 4;
    ushort4 o;
    if (row < N) {
        const float* p = x + (size_t)row * 130 + 2 + c4;
        float2 v0 = *(const float2*)p;
        float2 v1 = *(const float2*)(p + 2);
        o.x = (unsigned short)f2bf_bits(v0.x);
        o.y = (unsigned short)f2bf_bits(v0.y);
        o.z = (unsigned short)f2bf_bits(v1.x);
        o.w = (unsigned short)f2bf_bits(v1.y);
    } else {
        o = make_ushort4(0, 0, 0, 0);
        *(ushort4*)&featsbf[(size_t)row * C + c4] = o;   // zero pad rows of layer-2 input
    }
    *(ushort4*)&xA[(size_t)row * C + c4] = o;
}

__global__ void convert_w(const float* __restrict__ W1, const float* __restrict__ W2,
                          unsigned short* __restrict__ Wt1, unsigned short* __restrict__ Wt2) {
    int i = blockIdx.x * blockDim.x + threadIdx.x;
    if (i >= 128 * 512) return;
    int c = i >> 7, k = i & 127;
    Wt1[i] = (unsigned short)f2bf_bits(W1[(size_t)k * FOUT + c]);
    Wt2[i] = (unsigned short)f2bf_bits(W2[(size_t)k * FOUT + c]);
}

// ---------------- MFMA GEMM + fused alpha ----------------
// xh output layout: 8 slabs [h*2+chalf][Npad][64ch] bf16 (for XCD-local aggregation)
__global__ __launch_bounds__(256) void gemm_mfma(const unsigned short* __restrict__ A,
                                                 const unsigned short* __restrict__ Bt,
                                                 const float* __restrict__ a_src,
                                                 const float* __restrict__ a_dst,
                                                 unsigned short* __restrict__ Cb,
                                                 float* __restrict__ alpha_s,
                                                 float* __restrict__ alpha_d,
                                                 int Nrows, int Npad) {
    __shared__ unsigned short As[128 * 128];  // [row][k], 16B-chunk XOR-swizzled
    __shared__ unsigned short Bs[128 * 128];  // [colLocal][k], same swizzle
    int t = threadIdx.x;
    int lane = t & 63;
    int wv = t >> 6;
    int wr = wv >> 1, wc = wv & 1;
    int lr = lane & 15;
    int ksel = lane >> 4;
    int h = blockIdx.x;
    int r0 = blockIdx.y * 128;

    {
        const uint4* Ag = (const uint4*)(A + (size_t)r0 * C);
        const uint4* Bg = (const uint4*)(Bt + (size_t)h * 128 * C);
        uint4* AsV = (uint4*)As;
        uint4* BsV = (uint4*)Bs;
        #pragma unroll
        for (int i = 0; i < 8; ++i) {
            int q = t + i * 256;
            int row = q >> 4, cb = q & 15;
            AsV[row * 16 + (cb ^ (row & 7))] = Ag[q];
            BsV[row * 16 + (cb ^ (row & 7))] = Bg[q];
        }
    }
    __syncthreads();

    f32x4 acc[4][4];
    #pragma unroll
    for (int i = 0; i < 4; ++i)
        #pragma unroll
        for (int j = 0; j < 4; ++j) acc[i][j] = (f32x4){0.f, 0.f, 0.f, 0.f};

    #pragma unroll
    for (int ks = 0; ks < 4; ++ks) {
        int cb = ks * 4 + ksel;
        s16x8 af[4], bf[4];
        #pragma unroll
        for (int i = 0; i < 4; ++i) {
            int row = wr * 64 + i * 16 + lr;
            af[i] = *(const s16x8*)&As[row * C + (cb ^ (row & 7)) * 8];
            int col = wc * 64 + i * 16 + lr;
            bf[i] = *(const s16x8*)&Bs[col * C + (cb ^ (col & 7)) * 8];
        }
        #pragma unroll
        for (int i = 0; i < 4; ++i)
            #pragma unroll
            for (int j = 0; j < 4; ++j)
                acc[i][j] = __builtin_amdgcn_mfma_f32_16x16x32_bf16(af[i], bf[j], acc[i][j], 0, 0, 0);
    }
    __syncthreads();

    // transpose C frags into As as bf16 [row][col], byte-swizzled
    #pragma unroll
    for (int i = 0; i < 4; ++i) {
        #pragma unroll
        for (int j = 0; j < 4; ++j) {
            int col = wc * 64 + j * 16 + lr;
            #pragma unroll
            for (int r = 0; r < 4; ++r) {
                int row = wr * 64 + i * 16 + ksel * 4 + r;
                int boff = (row * 256 + col * 2) ^ ((row & 7) << 4);
                *(unsigned short*)((char*)As + boff) = (unsigned short)f2bf_bits(acc[i][j][r]);
            }
        }
    }
    __syncthreads();

    // coalesced store (slab layout) + fused alpha reduction
    int cb = t & 15, rb = t >> 4;
    float4 av0 = *(const float4*)&a_src[h * C + cb * 8];
    float4 av1 = *(const float4*)&a_src[h * C + cb * 8 + 4];
    float4 dv0 = *(const float4*)&a_dst[h * C + cb * 8];
    float4 dv1 = *(const float4*)&a_dst[h * C + cb * 8 + 4];
    #pragma unroll
    for (int i = 0; i < 8; ++i) {
        int row = rb + i * 16;
        uint4 v = ((const uint4*)As)[row * 16 + (cb ^ (row & 7))];
        float f0 = bflo(v.x), f1 = bfhi(v.x), f2 = bflo(v.y), f3 = bfhi(v.y);
        float f4 = bflo(v.z), f5 = bfhi(v.z), f6 = bflo(v.w), f7 = bfhi(v.w);
        float ps = f0 * av0.x + f1 * av0.y + f2 * av0.z + f3 * av0.w
                 + f4 * av1.x + f5 * av1.y + f6 * av1.z + f7 * av1.w;
        float pd = f0 * dv0.x + f1 * dv0.y + f2 * dv0.z + f3 * dv0.w
                 + f4 * dv1.x + f5 * dv1.y + f6 * dv1.z + f7 * dv1.w;
        ps += __shfl_xor(ps, 1); pd += __shfl_xor(pd, 1);
        ps += __shfl_xor(ps, 2); pd += __shfl_xor(pd, 2);
        ps += __shfl_xor(ps, 4); pd += __shfl_xor(pd, 4);
        ps += __shfl_xor(ps, 8); pd += __shfl_xor(pd, 8);
        int gr = r0 + row;
        if (gr < Nrows) {
            ((uint4*)Cb)[((size_t)(h * 2 + (cb >> 3)) * Npad + gr) * 8 + (cb & 7)] = v;
            if (cb == 0) {
                alpha_s[gr * H + h] = ps;
                alpha_d[gr * H + h] = pd;
            }
        }
    }
}

// ---------------- per-node max (monotone leaky trick: m = leaky(max as + ad)) ----------------
__global__ __launch_bounds__(256) void max_kernel(const float4* __restrict__ as4,
                                                  const float4* __restrict__ ad4,
                                                  const int* __restrict__ row_off,
                                                  const int* __restrict__ csr_src,
                                                  float4* __restrict__ mbuf, int N) {
    int n = blockIdx.x * 4 + (threadIdx.x >> 6);
    if (n >= N) return;
    int l = threadIdx.x & 63;
    int beg = row_off[n], end = row_off[n + 1];
    float4 mx = make_float4(-1e30f, -1e30f, -1e30f, -1e30f);
    for (int e = beg + l; e < end; e += 64) {
        float4 a = as4[csr_src[e]];
        mx.x = fmaxf(mx.x, a.x); mx.y = fmaxf(mx.y, a.y);
        mx.z = fmaxf(mx.z, a.z); mx.w = fmaxf(mx.w, a.w);
    }
    #pragma unroll
    for (int off = 32; off >= 1; off >>= 1) {
        mx.x = fmaxf(mx.x, __shfl_xor(mx.x, off));
        mx.y = fmaxf(mx.y, __shfl_xor(mx.y, off));
        mx.z = fmaxf(mx.z, __shfl_xor(mx.z, off));
        mx.w = fmaxf(mx.w, __shfl_xor(mx.w, off));
    }
    if (l == 0) {
        float4 d = ad4[n];
        float4 m;
        m.x = leaky(mx.x + d.x); m.y = leaky(mx.y + d.y);
        m.z = leaky(mx.z + d.z); m.w = leaky(mx.w + d.w);
        mbuf[n] = m;
    }
}

// ---------------- per-edge softmax weights, CSR order, [head][edge] slabs ----------------
__global__ void weight_kernel(const int* __restrict__ csr_src, const int* __restrict__ csr_dst,
                              int M,
                              const float4* __restrict__ as4, const float4* __restrict__ ad4,
                              const float4* __restrict__ m4, float* __restrict__ wts) {
    int e = blockIdx.x * blockDim.x + threadIdx.x;
    if (e >= M) return;
    int s = csr_src[e], d = csr_dst[e];
    float4 a = as4[s], b = ad4[d], m = m4[d];
    wts[e]                 = __expf(leaky(a.x + b.x) - m.x);
    wts[(size_t)M + e]     = __expf(leaky(a.y + b.y) - m.y);
    wts[(size_t)2 * M + e] = __expf(leaky(a.z + b.z) - m.z);
    wts[(size_t)3 * M + e] = __expf(leaky(a.w + b.w) - m.w);
}

// ---------------- aggregation: one (head,chalf) slab per block, XCD-pinned ----------------
// block: slab = blockIdx.x & 7 (-> XCD under round-robin dispatch); 8 nodes/block,
// 32 lanes per node covering 64 channels (dwords of bf16 pairs).
__global__ __launch_bounds__(256) void aggregate_v4(const unsigned short* __restrict__ xh_bf,
                                                    const float* __restrict__ wts,
                                                    const int* __restrict__ row_off,
                                                    const int* __restrict__ csr_src,
                                                    unsigned short* __restrict__ hout,
                                                    int N, int Npad, int M) {
    int i = blockIdx.x;
    int slab = i & 7;
    int h = slab >> 1;
    int t = threadIdx.x;
    int n = (i >> 3) * 8 + ((t >> 6) << 1) + ((t >> 5) & 1);
    if (n >= N) return;
    int ld = t & 31;
    int beg = row_off[n], end = row_off[n + 1];
    const unsigned int* xp = (const unsigned int*)xh_bf + (size_t)slab * Npad * 32;
    const float* wh = wts + (size_t)h * M;

    float acc0 = 0.f, acc1 = 0.f, acc2 = 0.f, acc3 = 0.f, den0 = 0.f, den1 = 0.f;
    int e = beg;
    for (; e + 1 < end; e += 2) {
        int s0 = csr_src[e], s1 = csr_src[e + 1];
        float w0 = wh[e], w1 = wh[e + 1];
        unsigned int v0 = xp[(size_t)s0 * 32 + ld];
        unsigned int v1 = xp[(size_t)s1 * 32 + ld];
        den0 += w0; den1 += w1;
        acc0 += w0 * bflo(v0); acc1 += w0 * bfhi(v0);
        acc2 += w1 * bflo(v1); acc3 += w1 * bfhi(v1);
    }
    if (e < end) {
        int s0 = csr_src[e];
        float w0 = wh[e];
        unsigned int v0 = xp[(size_t)s0 * 32 + ld];
        den0 += w0;
        acc0 += w0 * bflo(v0); acc1 += w0 * bfhi(v0);
    }
    float inv = 1.f / (den0 + den1);
    unsigned int o = f2bf_bits((acc0 + acc2) * inv) | (f2bf_bits((acc1 + acc3) * inv) << 16);
    ((unsigned int*)hout)[((size_t)slab * Npad + n) * 32 + ld] = o;
}

// ---------------- head mean + bias -> bf16 feats ----------------
__global__ void combine_kernel(const unsigned short* __restrict__ hout,
                               const float* __restrict__ bias,
                               unsigned short* __restrict__ featsbf, int N, int Npad) {
    int i = blockIdx.x * blockDim.x + threadIdx.x;   // dword index over [N][64]
    if (i >= N * 64) return;
    int n = i >> 6, c2 = i & 63;
    int chalf = c2 >> 5, ld = c2 & 31;
    const unsigned int* hp = (const unsigned int*)hout;
    float lo = 0.f, hi = 0.f;
    #pragma unroll
    for (int h = 0; h < 4; ++h) {
        unsigned int v = hp[((size_t)(h * 2 + chalf) * Npad + n) * 32 + ld];
        lo += bflo(v); hi += bfhi(v);
    }
    lo = 0.25f * lo + bias[c2 * 2];
    hi = 0.25f * hi + bias[c2 * 2 + 1];
    ((unsigned int*)featsbf)[(size_t)n * 64 + c2] = f2bf_bits(lo) | (f2bf_bits(hi) << 16);
}

// ---------------- pairwise scorer (bf16 feats) ----------------
__global__ __launch_bounds__(256) void pair_kernel(const unsigned short* __restrict__ featsbf,
                                                   const float* __restrict__ x,
                                                   const int* __restrict__ idx, int P,
                                                   const float* __restrict__ fc_w,
                                                   const float* __restrict__ fc_b,
                                                   float* __restrict__ out) {
    int p = blockIdx.x * 4 + (threadIdx.x >> 6);
    int l = threadIdx.x & 63;
    if (p >= P) return;
    int i0 = idx[p], i1 = idx[P + p];
    unsigned int a = ((const unsigned int*)featsbf)[(size_t)i0 * 64 + l];
    unsigned int b = ((const unsigned int*)featsbf)[(size_t)i1 * 64 + l];
    float s = bflo(a) * bflo(b) + bfhi(a) * bfhi(b);
    #pragma unroll
    for (int off = 32; off >= 1; off >>= 1) s += __shfl_xor(s, off);
    if (l == 0) {
        float dx = x[(size_t)i0 * 130] - x[(size_t)i1 * 130];
        float dy = x[(size_t)i0 * 130 + 1] - x[(size_t)i1 * 130 + 1];
        float pe = dx * dx + dy * dy;
        out[p] = fc_w[0] * s + fc_w[1] * pe + fc_b[0];
    }
}

extern "C" void kernel_launch(void* const* d_in, const int* in_sizes, int n_in,
                              void* d_out, int out_size, void* d_ws, size_t ws_size,
                              hipStream_t stream) {
    const float* x   = (const float*)d_in[0];
    const int*   ei  = (const int*)d_in[1];
    const int*   idx = (const int*)d_in[2];
    const float* W1  = (const float*)d_in[3];
    const float* as1 = (const float*)d_in[4];
    const float* ad1 = (const float*)d_in[5];
    const float* b1  = (const float*)d_in[6];
    const float* W2  = (const float*)d_in[7];
    const float* as2 = (const float*)d_in[8];
    const float* ad2 = (const float*)d_in[9];
    const float* b2  = (const float*)d_in[10];
    const float* fcw = (const float*)d_in[11];
    const float* fcb = (const float*)d_in[12];
    float* out = (float*)d_out;

    const int N = in_sizes[0] / 130;
    const int E = in_sizes[1] / 2;
    const int P = in_sizes[2] / 2;
    const int M = E + N;
    const int Npad = (N + 127) & ~127;

    char* ws = (char*)d_ws;
    size_t off = 0;
    auto alloc = [&](size_t bytes) -> void* {
        void* p = ws + off;
        off += (bytes + 255) & ~(size_t)255;
        return p;
    };
    unsigned short* xh_bf   = (unsigned short*)alloc((size_t)Npad * FOUT * 2);
    unsigned short* hout    = (unsigned short*)alloc((size_t)Npad * FOUT * 2);
    unsigned short* xA      = (unsigned short*)alloc((size_t)Npad * C * 2);
    unsigned short* featsbf = (unsigned short*)alloc((size_t)Npad * C * 2);
    unsigned short* Wt1     = (unsigned short*)alloc((size_t)128 * FOUT * 2);
    unsigned short* Wt2     = (unsigned short*)alloc((size_t)128 * FOUT * 2);
    float*          alpha_s = (float*)alloc((size_t)N * H * 4);
    float*          alpha_d = (float*)alloc((size_t)N * H * 4);
    float*          mbuf    = (float*)alloc((size_t)N * H * 4);
    float*          wts     = (float*)alloc((size_t)M * H * 4);
    int*            row_off = (int*)alloc((size_t)(N + 1) * 4);
    int*            cursor  = (int*)alloc((size_t)N * 4);
    int*            counts  = (int*)alloc((size_t)N * 4);
    int*            csr_src = (int*)alloc((size_t)M * 4);
    int*            csr_dst = (int*)alloc((size_t)M * 4);

    // CSR by dst (shared across both layers)
    zero_i32<<<(N + 255) / 256, 256, 0, stream>>>(counts, N);
    hist_kernel<<<(M + 255) / 256, 256, 0, stream>>>(ei, E, N, counts);
    scan_kernel<<<1, 256, 0, stream>>>(counts, row_off, cursor, N);
    scatter_kernel<<<(M + 255) / 256, 256, 0, stream>>>(ei, E, N, cursor, csr_src, csr_dst);

    // input conversions
    convert_x<<<(Npad * (C / 4) + 255) / 256, 256, 0, stream>>>(x, xA, featsbf, N, Npad);
    convert_w<<<(128 * FOUT + 255) / 256, 256, 0, stream>>>(W1, W2, Wt1, Wt2);

    dim3 ggrid(H, Npad / 128);
    int aggGrid = ((N + 7) / 8) * 8;
    int cmbGrid = (N * 64 + 255) / 256;

    // layer 1
    gemm_mfma<<<ggrid, 256, 0, stream>>>(xA, Wt1, as1, ad1, xh_bf, alpha_s, alpha_d, N, Npad);
    max_kernel<<<(N + 3) / 4, 256, 0, stream>>>((const float4*)alpha_s, (const float4*)alpha_d,
                                                row_off, csr_src, (float4*)mbuf, N);
    weight_kernel<<<(M + 255) / 256, 256, 0, stream>>>(csr_src, csr_dst, M, (const float4*)alpha_s,
                                                       (const float4*)alpha_d, (const float4*)mbuf,
                                                       wts);
    aggregate_v4<<<aggGrid, 256, 0, stream>>>(xh_bf, wts, row_off, csr_src, hout, N, Npad, M);
    combine_kernel<<<cmbGrid, 256, 0, stream>>>(hout, b1, featsbf, N, Npad);

    // layer 2
    gemm_mfma<<<ggrid, 256, 0, stream>>>(featsbf, Wt2, as2, ad2, xh_bf, alpha_s, alpha_d, N, Npad);
    max_kernel<<<(N + 3) / 4, 256, 0, stream>>>((const float4*)alpha_s, (const float4*)alpha_d,
                                                row_off, csr_src, (float4*)mbuf, N);
    weight_kernel<<<(M + 255) / 256, 256, 0, stream>>>(csr_src, csr_dst, M, (const float4*)alpha_s,
                                                       (const float4*)alpha_d, (const float4*)mbuf,
                                                       wts);
    aggregate_v4<<<aggGrid, 256, 0, stream>>>(xh_bf, wts, row_off, csr_src, hout, N, Npad, M);
    combine_kernel<<<cmbGrid, 256, 0, stream>>>(hout, b2, featsbf, N, Npad);

    // pairwise output
    pair_kernel<<<(P + 3) / 4, 256, 0, stream>>>(featsbf, x, idx, P, fcw, fcb, out);
}

// Round 5
// 308.091 us; speedup vs baseline: 1.0220x; 1.0220x over previous
//
#include <hip/hip_runtime.h>

#define H 4
#define C 128
#define FOUT 512

typedef __attribute__((ext_vector_type(8))) short s16x8;
typedef __attribute__((ext_vector_type(4))) float f32x4;

__device__ __forceinline__ unsigned int f2bf_bits(float f) {
    unsigned int u = __float_as_uint(f);
    u += 0x7fffu + ((u >> 16) & 1u);
    return u >> 16;
}
__device__ __forceinline__ float bflo(unsigned int u) { return __uint_as_float(u << 16); }
__device__ __forceinline__ float bfhi(unsigned int u) { return __uint_as_float(u & 0xffff0000u); }
__device__ __forceinline__ float leaky(float x) { return (x >= 0.f) ? x : 0.2f * x; }

// ---------------- CSR build ----------------
__global__ void zero_i32(int* __restrict__ p, int n) {
    int i = blockIdx.x * blockDim.x + threadIdx.x;
    if (i < n) p[i] = 0;
}

__global__ void hist_kernel(const int* __restrict__ ei, int E, int N, int* __restrict__ counts) {
    int e = blockIdx.x * blockDim.x + threadIdx.x;
    int M = E + N;
    if (e >= M) return;
    int d = (e < E) ? ei[E + e] : (e - E);
    atomicAdd(&counts[d], 1);
}

__global__ __launch_bounds__(256) void scan_kernel(const int* __restrict__ counts,
                                                   int* __restrict__ row_off,
                                                   int* __restrict__ cursor, int N) {
    __shared__ int part[256];
    int t = threadIdx.x;
    int chunk = (N + 255) >> 8;
    int b = t * chunk; if (b > N) b = N;
    int e = b + chunk; if (e > N) e = N;
    int s = 0;
    for (int i = b; i < e; ++i) s += counts[i];
    part[t] = s;
    __syncthreads();
    for (int off = 1; off < 256; off <<= 1) {
        int v = (t >= off) ? part[t - off] : 0;
        __syncthreads();
        part[t] += v;
        __syncthreads();
    }
    int run = (t == 0) ? 0 : part[t - 1];
    for (int i = b; i < e; ++i) { row_off[i] = run; cursor[i] = run; run += counts[i]; }
    if (t == 255) row_off[N] = part[255];
}

__global__ void scatter_kernel(const int* __restrict__ ei, int E, int N,
                               int* __restrict__ cursor, int* __restrict__ csr_src,
                               int* __restrict__ csr_dst) {
    int e = blockIdx.x * blockDim.x + threadIdx.x;
    int M = E + N;
    if (e >= M) return;
    int s = (e < E) ? ei[e] : (e - E);
    int d = (e < E) ? ei[E + e] : (e - E);
    int pos = atomicAdd(&cursor[d], 1);
    csr_src[pos] = s;
    csr_dst[pos] = d;
}

// ---------------- input conversions ----------------
__global__ void convert_x(const float* __restrict__ x, unsigned short* __restrict__ xA,
                          unsigned short* __restrict__ featsbf, int N, int Npad) {
    int i = blockIdx.x * blockDim.x + threadIdx.x;  // one 4-channel group per thread
    int total = Npad * (C / 4);
    if (i >= total) return;
    int row = i >> 5;
    int c4 = (i & 31) * 4;
    ushort4 o;
    if (row < N) {
        const float* p = x + (size_t)row * 130 + 2 + c4;
        float2 v0 = *(const float2*)p;
        float2 v1 = *(const float2*)(p + 2);
        o.x = (unsigned short)f2bf_bits(v0.x);
        o.y = (unsigned short)f2bf_bits(v0.y);
        o.z = (unsigned short)f2bf_bits(v1.x);
        o.w = (unsigned short)f2bf_bits(v1.y);
    } else {
        o = make_ushort4(0, 0, 0, 0);
        *(ushort4*)&featsbf[(size_t)row * C + c4] = o;   // zero pad rows of layer-2 input
    }
    *(ushort4*)&xA[(size_t)row * C + c4] = o;
}

__global__ void convert_w(const float* __restrict__ W1, const float* __restrict__ W2,
                          unsigned short* __restrict__ Wt1, unsigned short* __restrict__ Wt2) {
    int i = blockIdx.x * blockDim.x + threadIdx.x;
    if (i >= 128 * 512) return;
    int c = i >> 7, k = i & 127;
    Wt1[i] = (unsigned short)f2bf_bits(W1[(size_t)k * FOUT + c]);
    Wt2[i] = (unsigned short)f2bf_bits(W2[(size_t)k * FOUT + c]);
}

// ---------------- MFMA GEMM + fused alpha ----------------
// xh output layout: 8 slabs [h*2+chalf][Npad][64ch] bf16 (for XCD-local aggregation)
__global__ __launch_bounds__(256) void gemm_mfma(const unsigned short* __restrict__ A,
                                                 const unsigned short* __restrict__ Bt,
                                                 const float* __restrict__ a_src,
                                                 const float* __restrict__ a_dst,
                                                 unsigned short* __restrict__ Cb,
                                                 float* __restrict__ alpha_s,
                                                 float* __restrict__ alpha_d,
                                                 int Nrows, int Npad) {
    __shared__ unsigned short As[128 * 128];  // [row][k], 16B-chunk XOR-swizzled
    __shared__ unsigned short Bs[128 * 128];  // [colLocal][k], same swizzle
    int t = threadIdx.x;
    int lane = t & 63;
    int wv = t >> 6;
    int wr = wv >> 1, wc = wv & 1;
    int lr = lane & 15;
    int ksel = lane >> 4;
    int h = blockIdx.x;
    int r0 = blockIdx.y * 128;

    {
        const uint4* Ag = (const uint4*)(A + (size_t)r0 * C);
        const uint4* Bg = (const uint4*)(Bt + (size_t)h * 128 * C);
        uint4* AsV = (uint4*)As;
        uint4* BsV = (uint4*)Bs;
        #pragma unroll
        for (int i = 0; i < 8; ++i) {
            int q = t + i * 256;
            int row = q >> 4, cb = q & 15;
            AsV[row * 16 + (cb ^ (row & 7))] = Ag[q];
            BsV[row * 16 + (cb ^ (row & 7))] = Bg[q];
        }
    }
    __syncthreads();

    f32x4 acc[4][4];
    #pragma unroll
    for (int i = 0; i < 4; ++i)
        #pragma unroll
        for (int j = 0; j < 4; ++j) acc[i][j] = (f32x4){0.f, 0.f, 0.f, 0.f};

    #pragma unroll
    for (int ks = 0; ks < 4; ++ks) {
        int cb = ks * 4 + ksel;
        s16x8 af[4], bf[4];
        #pragma unroll
        for (int i = 0; i < 4; ++i) {
            int row = wr * 64 + i * 16 + lr;
            af[i] = *(const s16x8*)&As[row * C + (cb ^ (row & 7)) * 8];
            int col = wc * 64 + i * 16 + lr;
            bf[i] = *(const s16x8*)&Bs[col * C + (cb ^ (col & 7)) * 8];
        }
        #pragma unroll
        for (int i = 0; i < 4; ++i)
            #pragma unroll
            for (int j = 0; j < 4; ++j)
                acc[i][j] = __builtin_amdgcn_mfma_f32_16x16x32_bf16(af[i], bf[j], acc[i][j], 0, 0, 0);
    }
    __syncthreads();

    // transpose C frags into As as bf16 [row][col], byte-swizzled
    #pragma unroll
    for (int i = 0; i < 4; ++i) {
        #pragma unroll
        for (int j = 0; j < 4; ++j) {
            int col = wc * 64 + j * 16 + lr;
            #pragma unroll
            for (int r = 0; r < 4; ++r) {
                int row = wr * 64 + i * 16 + ksel * 4 + r;
                int boff = (row * 256 + col * 2) ^ ((row & 7) << 4);
                *(unsigned short*)((char*)As + boff) = (unsigned short)f2bf_bits(acc[i][j][r]);
            }
        }
    }
    __syncthreads();

    // coalesced store (slab layout) + fused alpha reduction
    int cb = t & 15, rb = t >> 4;
    float4 av0 = *(const float4*)&a_src[h * C + cb * 8];
    float4 av1 = *(const float4*)&a_src[h * C + cb * 8 + 4];
    float4 dv0 = *(const float4*)&a_dst[h * C + cb * 8];
    float4 dv1 = *(const float4*)&a_dst[h * C + cb * 8 + 4];
    #pragma unroll
    for (int i = 0; i < 8; ++i) {
        int row = rb + i * 16;
        uint4 v = ((const uint4*)As)[row * 16 + (cb ^ (row & 7))];
        float f0 = bflo(v.x), f1 = bfhi(v.x), f2 = bflo(v.y), f3 = bfhi(v.y);
        float f4 = bflo(v.z), f5 = bfhi(v.z), f6 = bflo(v.w), f7 = bfhi(v.w);
        float ps = f0 * av0.x + f1 * av0.y + f2 * av0.z + f3 * av0.w
                 + f4 * av1.x + f5 * av1.y + f6 * av1.z + f7 * av1.w;
        float pd = f0 * dv0.x + f1 * dv0.y + f2 * dv0.z + f3 * dv0.w
                 + f4 * dv1.x + f5 * dv1.y + f6 * dv1.z + f7 * dv1.w;
        ps += __shfl_xor(ps, 1); pd += __shfl_xor(pd, 1);
        ps += __shfl_xor(ps, 2); pd += __shfl_xor(pd, 2);
        ps += __shfl_xor(ps, 4); pd += __shfl_xor(pd, 4);
        ps += __shfl_xor(ps, 8); pd += __shfl_xor(pd, 8);
        int gr = r0 + row;
        if (gr < Nrows) {
            ((uint4*)Cb)[((size_t)(h * 2 + (cb >> 3)) * Npad + gr) * 8 + (cb & 7)] = v;
            if (cb == 0) {
                alpha_s[gr * H + h] = ps;
                alpha_d[gr * H + h] = pd;
            }
        }
    }
}

// ---------------- per-node max (monotone leaky trick: m = leaky(max as + ad)) ----------------
__global__ __launch_bounds__(256) void max_kernel(const float4* __restrict__ as4,
                                                  const float4* __restrict__ ad4,
                                                  const int* __restrict__ row_off,
                                                  const int* __restrict__ csr_src,
                                                  float4* __restrict__ mbuf, int N) {
    int n = blockIdx.x * 4 + (threadIdx.x >> 6);
    if (n >= N) return;
    int l = threadIdx.x & 63;
    int beg = row_off[n], end = row_off[n + 1];
    float4 mx = make_float4(-1e30f, -1e30f, -1e30f, -1e30f);
    for (int e = beg + l; e < end; e += 64) {
        float4 a = as4[csr_src[e]];
        mx.x = fmaxf(mx.x, a.x); mx.y = fmaxf(mx.y, a.y);
        mx.z = fmaxf(mx.z, a.z); mx.w = fmaxf(mx.w, a.w);
    }
    #pragma unroll
    for (int off = 32; off >= 1; off >>= 1) {
        mx.x = fmaxf(mx.x, __shfl_xor(mx.x, off));
        mx.y = fmaxf(mx.y, __shfl_xor(mx.y, off));
        mx.z = fmaxf(mx.z, __shfl_xor(mx.z, off));
        mx.w = fmaxf(mx.w, __shfl_xor(mx.w, off));
    }
    if (l == 0) {
        float4 d = ad4[n];
        float4 m;
        m.x = leaky(mx.x + d.x); m.y = leaky(mx.y + d.y);
        m.z = leaky(mx.z + d.z); m.w = leaky(mx.w + d.w);
        mbuf[n] = m;
    }
}

// ---------------- per-edge packed (src, weight) per head: pk[h][e] = {src, w_bits} ----------------
__global__ void weight_kernel(const int* __restrict__ csr_src, const int* __restrict__ csr_dst,
                              int M,
                              const float4* __restrict__ as4, const float4* __restrict__ ad4,
                              const float4* __restrict__ m4, uint2* __restrict__ pk) {
    int e = blockIdx.x * blockDim.x + threadIdx.x;
    if (e >= M) return;
    int s = csr_src[e], d = csr_dst[e];
    float4 a = as4[s], b = ad4[d], m = m4[d];
    unsigned int su = (unsigned int)s;
    pk[e]                 = make_uint2(su, __float_as_uint(__expf(leaky(a.x + b.x) - m.x)));
    pk[(size_t)M + e]     = make_uint2(su, __float_as_uint(__expf(leaky(a.y + b.y) - m.y)));
    pk[(size_t)2 * M + e] = make_uint2(su, __float_as_uint(__expf(leaky(a.z + b.z) - m.z)));
    pk[(size_t)3 * M + e] = make_uint2(su, __float_as_uint(__expf(leaky(a.w + b.w) - m.w)));
}

// ---------------- aggregation: one (head,chalf) slab per block, XCD-pinned, unroll-4 ----------------
__global__ __launch_bounds__(256) void aggregate_v5(const unsigned short* __restrict__ xh_bf,
                                                    const uint2* __restrict__ pk,
                                                    const int* __restrict__ row_off,
                                                    unsigned short* __restrict__ hout,
                                                    int N, int Npad, int M) {
    int i = blockIdx.x;
    int slab = i & 7;
    int h = slab >> 1;
    int t = threadIdx.x;
    int n = (i >> 3) * 8 + ((t >> 6) << 1) + ((t >> 5) & 1);
    if (n >= N) return;
    int ld = t & 31;
    int beg = row_off[n], end = row_off[n + 1];
    const unsigned int* xp = (const unsigned int*)xh_bf + (size_t)slab * Npad * 32 + ld;
    const uint2* ph = pk + (size_t)h * M;

    float acc0 = 0.f, acc1 = 0.f, acc2 = 0.f, acc3 = 0.f, den0 = 0.f, den1 = 0.f;
    int e = beg;
    for (; e + 3 < end; e += 4) {
        uint2 p0 = ph[e];
        uint2 p1 = ph[e + 1];
        uint2 p2 = ph[e + 2];
        uint2 p3 = ph[e + 3];
        unsigned int v0 = xp[(size_t)p0.x * 32];
        unsigned int v1 = xp[(size_t)p1.x * 32];
        unsigned int v2 = xp[(size_t)p2.x * 32];
        unsigned int v3 = xp[(size_t)p3.x * 32];
        float w0 = __uint_as_float(p0.y), w1 = __uint_as_float(p1.y);
        float w2 = __uint_as_float(p2.y), w3 = __uint_as_float(p3.y);
        den0 += w0 + w2; den1 += w1 + w3;
        acc0 += w0 * bflo(v0); acc1 += w0 * bfhi(v0);
        acc2 += w1 * bflo(v1); acc3 += w1 * bfhi(v1);
        acc0 += w2 * bflo(v2); acc1 += w2 * bfhi(v2);
        acc2 += w3 * bflo(v3); acc3 += w3 * bfhi(v3);
    }
    for (; e < end; ++e) {
        uint2 p0 = ph[e];
        unsigned int v0 = xp[(size_t)p0.x * 32];
        float w0 = __uint_as_float(p0.y);
        den0 += w0;
        acc0 += w0 * bflo(v0); acc1 += w0 * bfhi(v0);
    }
    float inv = 1.f / (den0 + den1);
    unsigned int o = f2bf_bits((acc0 + acc2) * inv) | (f2bf_bits((acc1 + acc3) * inv) << 16);
    ((unsigned int*)hout)[((size_t)slab * Npad + n) * 32 + ld] = o;
}

// ---------------- head mean + bias -> bf16 feats ----------------
__global__ void combine_kernel(const unsigned short* __restrict__ hout,
                               const float* __restrict__ bias,
                               unsigned short* __restrict__ featsbf, int N, int Npad) {
    int i = blockIdx.x * blockDim.x + threadIdx.x;   // dword index over [N][64]
    if (i >= N * 64) return;
    int n = i >> 6, c2 = i & 63;
    int chalf = c2 >> 5, ld = c2 & 31;
    const unsigned int* hp = (const unsigned int*)hout;
    float lo = 0.f, hi = 0.f;
    #pragma unroll
    for (int h = 0; h < 4; ++h) {
        unsigned int v = hp[((size_t)(h * 2 + chalf) * Npad + n) * 32 + ld];
        lo += bflo(v); hi += bfhi(v);
    }
    lo = 0.25f * lo + bias[c2 * 2];
    hi = 0.25f * hi + bias[c2 * 2 + 1];
    ((unsigned int*)featsbf)[(size_t)n * 64 + c2] = f2bf_bits(lo) | (f2bf_bits(hi) << 16);
}

// ---------------- pairwise scorer (bf16 feats) ----------------
__global__ __launch_bounds__(256) void pair_kernel(const unsigned short* __restrict__ featsbf,
                                                   const float* __restrict__ x,
                                                   const int* __restrict__ idx, int P,
                                                   const float* __restrict__ fc_w,
                                                   const float* __restrict__ fc_b,
                                                   float* __restrict__ out) {
    int p = blockIdx.x * 4 + (threadIdx.x >> 6);
    int l = threadIdx.x & 63;
    if (p >= P) return;
    int i0 = idx[p], i1 = idx[P + p];
    unsigned int a = ((const unsigned int*)featsbf)[(size_t)i0 * 64 + l];
    unsigned int b = ((const unsigned int*)featsbf)[(size_t)i1 * 64 + l];
    float s = bflo(a) * bflo(b) + bfhi(a) * bfhi(b);
    #pragma unroll
    for (int off = 32; off >= 1; off >>= 1) s += __shfl_xor(s, off);
    if (l == 0) {
        float dx = x[(size_t)i0 * 130] - x[(size_t)i1 * 130];
        float dy = x[(size_t)i0 * 130 + 1] - x[(size_t)i1 * 130 + 1];
        float pe = dx * dx + dy * dy;
        out[p] = fc_w[0] * s + fc_w[1] * pe + fc_b[0];
    }
}

extern "C" void kernel_launch(void* const* d_in, const int* in_sizes, int n_in,
                              void* d_out, int out_size, void* d_ws, size_t ws_size,
                              hipStream_t stream) {
    const float* x   = (const float*)d_in[0];
    const int*   ei  = (const int*)d_in[1];
    const int*   idx = (const int*)d_in[2];
    const float* W1  = (const float*)d_in[3];
    const float* as1 = (const float*)d_in[4];
    const float* ad1 = (const float*)d_in[5];
    const float* b1  = (const float*)d_in[6];
    const float* W2  = (const float*)d_in[7];
    const float* as2 = (const float*)d_in[8];
    const float* ad2 = (const float*)d_in[9];
    const float* b2  = (const float*)d_in[10];
    const float* fcw = (const float*)d_in[11];
    const float* fcb = (const float*)d_in[12];
    float* out = (float*)d_out;

    const int N = in_sizes[0] / 130;
    const int E = in_sizes[1] / 2;
    const int P = in_sizes[2] / 2;
    const int M = E + N;
    const int Npad = (N + 127) & ~127;

    char* ws = (char*)d_ws;
    size_t off = 0;
    auto alloc = [&](size_t bytes) -> void* {
        void* p = ws + off;
        off += (bytes + 255) & ~(size_t)255;
        return p;
    };
    unsigned short* xh_bf   = (unsigned short*)alloc((size_t)Npad * FOUT * 2);
    unsigned short* hout    = (unsigned short*)alloc((size_t)Npad * FOUT * 2);
    unsigned short* xA      = (unsigned short*)alloc((size_t)Npad * C * 2);
    unsigned short* featsbf = (unsigned short*)alloc((size_t)Npad * C * 2);
    unsigned short* Wt1     = (unsigned short*)alloc((size_t)128 * FOUT * 2);
    unsigned short* Wt2     = (unsigned short*)alloc((size_t)128 * FOUT * 2);
    float*          alpha_s = (float*)alloc((size_t)N * H * 4);
    float*          alpha_d = (float*)alloc((size_t)N * H * 4);
    float*          mbuf    = (float*)alloc((size_t)N * H * 4);
    uint2*          pk      = (uint2*)alloc((size_t)M * H * 8);
    int*            row_off = (int*)alloc((size_t)(N + 1) * 4);
    int*            cursor  = (int*)alloc((size_t)N * 4);
    int*            counts  = (int*)alloc((size_t)N * 4);
    int*            csr_src = (int*)alloc((size_t)M * 4);
    int*            csr_dst = (int*)alloc((size_t)M * 4);

    // CSR by dst (shared across both layers)
    zero_i32<<<(N + 255) / 256, 256, 0, stream>>>(counts, N);
    hist_kernel<<<(M + 255) / 256, 256, 0, stream>>>(ei, E, N, counts);
    scan_kernel<<<1, 256, 0, stream>>>(counts, row_off, cursor, N);
    scatter_kernel<<<(M + 255) / 256, 256, 0, stream>>>(ei, E, N, cursor, csr_src, csr_dst);

    // input conversions
    convert_x<<<(Npad * (C / 4) + 255) / 256, 256, 0, stream>>>(x, xA, featsbf, N, Npad);
    convert_w<<<(128 * FOUT + 255) / 256, 256, 0, stream>>>(W1, W2, Wt1, Wt2);

    dim3 ggrid(H, Npad / 128);
    int aggGrid = ((N + 7) / 8) * 8;
    int cmbGrid = (N * 64 + 255) / 256;

    // layer 1
    gemm_mfma<<<ggrid, 256, 0, stream>>>(xA, Wt1, as1, ad1, xh_bf, alpha_s, alpha_d, N, Npad);
    max_kernel<<<(N + 3) / 4, 256, 0, stream>>>((const float4*)alpha_s, (const float4*)alpha_d,
                                                row_off, csr_src, (float4*)mbuf, N);
    weight_kernel<<<(M + 255) / 256, 256, 0, stream>>>(csr_src, csr_dst, M, (const float4*)alpha_s,
                                                       (const float4*)alpha_d, (const float4*)mbuf,
                                                       pk);
    aggregate_v5<<<aggGrid, 256, 0, stream>>>(xh_bf, pk, row_off, hout, N, Npad, M);
    combine_kernel<<<cmbGrid, 256, 0, stream>>>(hout, b1, featsbf, N, Npad);

    // layer 2
    gemm_mfma<<<ggrid, 256, 0, stream>>>(featsbf, Wt2, as2, ad2, xh_bf, alpha_s, alpha_d, N, Npad);
    max_kernel<<<(N + 3) / 4, 256, 0, stream>>>((const float4*)alpha_s, (const float4*)alpha_d,
                                                row_off, csr_src, (float4*)mbuf, N);
    weight_kernel<<<(M + 255) / 256, 256, 0, stream>>>(csr_src, csr_dst, M, (const float4*)alpha_s,
                                                       (const float4*)alpha_d, (const float4*)mbuf,
                                                       pk);
    aggregate_v5<<<aggGrid, 256, 0, stream>>>(xh_bf, pk, row_off, hout, N, Npad, M);
    combine_kernel<<<cmbGrid, 256, 0, stream>>>(hout, b2, featsbf, N, Npad);

    // pairwise output
    pair_kernel<<<(P + 3) / 4, 256, 0, stream>>>(featsbf, x, idx, P, fcw, fcb, out);
}

// Round 6
// 292.841 us; speedup vs baseline: 1.0752x; 1.0521x over previous
//
#include <hip/hip_runtime.h>

#define H 4
#define C 128
#define FOUT 512

typedef __attribute__((ext_vector_type(8))) short s16x8;
typedef __attribute__((ext_vector_type(4))) float f32x4;
typedef __attribute__((ext_vector_type(4))) int i32x4;
typedef __attribute__((ext_vector_type(2))) int i32x2;

// CK-style raw buffer-load intrinsics (32-bit voffset addressing)
__device__ int amd_buf_load_i32(i32x4 rsrc, int voffset, int soffset, int aux) __asm("llvm.amdgcn.raw.buffer.load.i32");
__device__ i32x2 amd_buf_load_i32x2(i32x4 rsrc, int voffset, int soffset, int aux) __asm("llvm.amdgcn.raw.buffer.load.v2i32");

__device__ __forceinline__ i32x4 make_rsrc(const void* p, unsigned int bytes) {
    i32x4 r;
    r.x = (int)(unsigned int)(unsigned long long)p;
    r.y = (int)(unsigned int)(((unsigned long long)p) >> 32);
    r.z = (int)bytes;          // num_records (stride==0 -> bytes)
    r.w = 0x00020000;          // raw untyped dword access
    return r;
}

__device__ __forceinline__ unsigned int f2bf_bits(float f) {
    unsigned int u = __float_as_uint(f);
    u += 0x7fffu + ((u >> 16) & 1u);
    return u >> 16;
}
__device__ __forceinline__ float bflo(unsigned int u) { return __uint_as_float(u << 16); }
__device__ __forceinline__ float bfhi(unsigned int u) { return __uint_as_float(u & 0xffff0000u); }
__device__ __forceinline__ float leaky(float x) { return (x >= 0.f) ? x : 0.2f * x; }

// ---------------- CSR build ----------------
__global__ void zero_i32(int* __restrict__ p, int n) {
    int i = blockIdx.x * blockDim.x + threadIdx.x;
    if (i < n) p[i] = 0;
}

__global__ void hist_kernel(const int* __restrict__ ei, int E, int N, int* __restrict__ counts) {
    int e = blockIdx.x * blockDim.x + threadIdx.x;
    int M = E + N;
    if (e >= M) return;
    int d = (e < E) ? ei[E + e] : (e - E);
    atomicAdd(&counts[d], 1);
}

__global__ __launch_bounds__(256) void scan_kernel(const int* __restrict__ counts,
                                                   int* __restrict__ row_off,
                                                   int* __restrict__ cursor, int N) {
    __shared__ int part[256];
    int t = threadIdx.x;
    int chunk = (N + 255) >> 8;
    int b = t * chunk; if (b > N) b = N;
    int e = b + chunk; if (e > N) e = N;
    int s = 0;
    for (int i = b; i < e; ++i) s += counts[i];
    part[t] = s;
    __syncthreads();
    for (int off = 1; off < 256; off <<= 1) {
        int v = (t >= off) ? part[t - off] : 0;
        __syncthreads();
        part[t] += v;
        __syncthreads();
    }
    int run = (t == 0) ? 0 : part[t - 1];
    for (int i = b; i < e; ++i) { row_off[i] = run; cursor[i] = run; run += counts[i]; }
    if (t == 255) row_off[N] = part[255];
}

__global__ void scatter_kernel(const int* __restrict__ ei, int E, int N,
                               int* __restrict__ cursor, int* __restrict__ csr_src,
                               int* __restrict__ csr_dst) {
    int e = blockIdx.x * blockDim.x + threadIdx.x;
    int M = E + N;
    if (e >= M) return;
    int s = (e < E) ? ei[e] : (e - E);
    int d = (e < E) ? ei[E + e] : (e - E);
    int pos = atomicAdd(&cursor[d], 1);
    csr_src[pos] = s;
    csr_dst[pos] = d;
}

// ---------------- input conversions ----------------
__global__ void convert_x(const float* __restrict__ x, unsigned short* __restrict__ xA,
                          unsigned short* __restrict__ featsbf, int N, int Npad) {
    int i = blockIdx.x * blockDim.x + threadIdx.x;  // one 4-channel group per thread
    int total = Npad * (C / 4);
    if (i >= total) return;
    int row = i >> 5;
    int c4 = (i & 31) * 4;
    ushort4 o;
    if (row < N) {
        const float* p = x + (size_t)row * 130 + 2 + c4;
        float2 v0 = *(const float2*)p;
        float2 v1 = *(const float2*)(p + 2);
        o.x = (unsigned short)f2bf_bits(v0.x);
        o.y = (unsigned short)f2bf_bits(v0.y);
        o.z = (unsigned short)f2bf_bits(v1.x);
        o.w = (unsigned short)f2bf_bits(v1.y);
    } else {
        o = make_ushort4(0, 0, 0, 0);
        *(ushort4*)&featsbf[(size_t)row * C + c4] = o;   // zero pad rows of layer-2 input
    }
    *(ushort4*)&xA[(size_t)row * C + c4] = o;
}

__global__ void convert_w(const float* __restrict__ W1, const float* __restrict__ W2,
                          unsigned short* __restrict__ Wt1, unsigned short* __restrict__ Wt2) {
    int i = blockIdx.x * blockDim.x + threadIdx.x;
    if (i >= 128 * 512) return;
    int c = i >> 7, k = i & 127;
    Wt1[i] = (unsigned short)f2bf_bits(W1[(size_t)k * FOUT + c]);
    Wt2[i] = (unsigned short)f2bf_bits(W2[(size_t)k * FOUT + c]);
}

// ---------------- MFMA GEMM + fused alpha ----------------
// xh output layout: 8 slabs [h*2+chalf][Npad][64ch] bf16 (for XCD-local aggregation)
__global__ __launch_bounds__(256) void gemm_mfma(const unsigned short* __restrict__ A,
                                                 const unsigned short* __restrict__ Bt,
                                                 const float* __restrict__ a_src,
                                                 const float* __restrict__ a_dst,
                                                 unsigned short* __restrict__ Cb,
                                                 float* __restrict__ alpha_s,
                                                 float* __restrict__ alpha_d,
                                                 int Nrows, int Npad) {
    __shared__ unsigned short As[128 * 128];  // [row][k], 16B-chunk XOR-swizzled
    __shared__ unsigned short Bs[128 * 128];  // [colLocal][k], same swizzle
    int t = threadIdx.x;
    int lane = t & 63;
    int wv = t >> 6;
    int wr = wv >> 1, wc = wv & 1;
    int lr = lane & 15;
    int ksel = lane >> 4;
    int h = blockIdx.x;
    int r0 = blockIdx.y * 128;

    {
        const uint4* Ag = (const uint4*)(A + (size_t)r0 * C);
        const uint4* Bg = (const uint4*)(Bt + (size_t)h * 128 * C);
        uint4* AsV = (uint4*)As;
        uint4* BsV = (uint4*)Bs;
        #pragma unroll
        for (int i = 0; i < 8; ++i) {
            int q = t + i * 256;
            int row = q >> 4, cb = q & 15;
            AsV[row * 16 + (cb ^ (row & 7))] = Ag[q];
            BsV[row * 16 + (cb ^ (row & 7))] = Bg[q];
        }
    }
    __syncthreads();

    f32x4 acc[4][4];
    #pragma unroll
    for (int i = 0; i < 4; ++i)
        #pragma unroll
        for (int j = 0; j < 4; ++j) acc[i][j] = (f32x4){0.f, 0.f, 0.f, 0.f};

    #pragma unroll
    for (int ks = 0; ks < 4; ++ks) {
        int cb = ks * 4 + ksel;
        s16x8 af[4], bf[4];
        #pragma unroll
        for (int i = 0; i < 4; ++i) {
            int row = wr * 64 + i * 16 + lr;
            af[i] = *(const s16x8*)&As[row * C + (cb ^ (row & 7)) * 8];
            int col = wc * 64 + i * 16 + lr;
            bf[i] = *(const s16x8*)&Bs[col * C + (cb ^ (col & 7)) * 8];
        }
        #pragma unroll
        for (int i = 0; i < 4; ++i)
            #pragma unroll
            for (int j = 0; j < 4; ++j)
                acc[i][j] = __builtin_amdgcn_mfma_f32_16x16x32_bf16(af[i], bf[j], acc[i][j], 0, 0, 0);
    }
    __syncthreads();

    // transpose C frags into As as bf16 [row][col], byte-swizzled
    #pragma unroll
    for (int i = 0; i < 4; ++i) {
        #pragma unroll
        for (int j = 0; j < 4; ++j) {
            int col = wc * 64 + j * 16 + lr;
            #pragma unroll
            for (int r = 0; r < 4; ++r) {
                int row = wr * 64 + i * 16 + ksel * 4 + r;
                int boff = (row * 256 + col * 2) ^ ((row & 7) << 4);
                *(unsigned short*)((char*)As + boff) = (unsigned short)f2bf_bits(acc[i][j][r]);
            }
        }
    }
    __syncthreads();

    // coalesced store (slab layout) + fused alpha reduction
    int cb = t & 15, rb = t >> 4;
    float4 av0 = *(const float4*)&a_src[h * C + cb * 8];
    float4 av1 = *(const float4*)&a_src[h * C + cb * 8 + 4];
    float4 dv0 = *(const float4*)&a_dst[h * C + cb * 8];
    float4 dv1 = *(const float4*)&a_dst[h * C + cb * 8 + 4];
    #pragma unroll
    for (int i = 0; i < 8; ++i) {
        int row = rb + i * 16;
        uint4 v = ((const uint4*)As)[row * 16 + (cb ^ (row & 7))];
        float f0 = bflo(v.x), f1 = bfhi(v.x), f2 = bflo(v.y), f3 = bfhi(v.y);
        float f4 = bflo(v.z), f5 = bfhi(v.z), f6 = bflo(v.w), f7 = bfhi(v.w);
        float ps = f0 * av0.x + f1 * av0.y + f2 * av0.z + f3 * av0.w
                 + f4 * av1.x + f5 * av1.y + f6 * av1.z + f7 * av1.w;
        float pd = f0 * dv0.x + f1 * dv0.y + f2 * dv0.z + f3 * dv0.w
                 + f4 * dv1.x + f5 * dv1.y + f6 * dv1.z + f7 * dv1.w;
        ps += __shfl_xor(ps, 1); pd += __shfl_xor(pd, 1);
        ps += __shfl_xor(ps, 2); pd += __shfl_xor(pd, 2);
        ps += __shfl_xor(ps, 4); pd += __shfl_xor(pd, 4);
        ps += __shfl_xor(ps, 8); pd += __shfl_xor(pd, 8);
        int gr = r0 + row;
        if (gr < Nrows) {
            ((uint4*)Cb)[((size_t)(h * 2 + (cb >> 3)) * Npad + gr) * 8 + (cb & 7)] = v;
            if (cb == 0) {
                alpha_s[gr * H + h] = ps;
                alpha_d[gr * H + h] = pd;
            }
        }
    }
}

// ---------------- per-node max (monotone leaky trick: m = leaky(max as + ad)) ----------------
__global__ __launch_bounds__(256) void max_kernel(const float4* __restrict__ as4,
                                                  const float4* __restrict__ ad4,
                                                  const int* __restrict__ row_off,
                                                  const int* __restrict__ csr_src,
                                                  float4* __restrict__ mbuf, int N) {
    int n = blockIdx.x * 4 + (threadIdx.x >> 6);
    if (n >= N) return;
    int l = threadIdx.x & 63;
    int beg = row_off[n], end = row_off[n + 1];
    float4 mx = make_float4(-1e30f, -1e30f, -1e30f, -1e30f);
    for (int e = beg + l; e < end; e += 64) {
        float4 a = as4[csr_src[e]];
        mx.x = fmaxf(mx.x, a.x); mx.y = fmaxf(mx.y, a.y);
        mx.z = fmaxf(mx.z, a.z); mx.w = fmaxf(mx.w, a.w);
    }
    #pragma unroll
    for (int off = 32; off >= 1; off >>= 1) {
        mx.x = fmaxf(mx.x, __shfl_xor(mx.x, off));
        mx.y = fmaxf(mx.y, __shfl_xor(mx.y, off));
        mx.z = fmaxf(mx.z, __shfl_xor(mx.z, off));
        mx.w = fmaxf(mx.w, __shfl_xor(mx.w, off));
    }
    if (l == 0) {
        float4 d = ad4[n];
        float4 m;
        m.x = leaky(mx.x + d.x); m.y = leaky(mx.y + d.y);
        m.z = leaky(mx.z + d.z); m.w = leaky(mx.w + d.w);
        mbuf[n] = m;
    }
}

// ---------------- per-edge packed (src, weight) per head: pk[h][e] = {src, w_bits} ----------------
__global__ void weight_kernel(const int* __restrict__ csr_src, const int* __restrict__ csr_dst,
                              int M,
                              const float4* __restrict__ as4, const float4* __restrict__ ad4,
                              const float4* __restrict__ m4, uint2* __restrict__ pk) {
    int e = blockIdx.x * blockDim.x + threadIdx.x;
    if (e >= M) return;
    int s = csr_src[e], d = csr_dst[e];
    float4 a = as4[s], b = ad4[d], m = m4[d];
    unsigned int su = (unsigned int)s;
    pk[e]                 = make_uint2(su, __float_as_uint(__expf(leaky(a.x + b.x) - m.x)));
    pk[(size_t)M + e]     = make_uint2(su, __float_as_uint(__expf(leaky(a.y + b.y) - m.y)));
    pk[(size_t)2 * M + e] = make_uint2(su, __float_as_uint(__expf(leaky(a.z + b.z) - m.z)));
    pk[(size_t)3 * M + e] = make_uint2(su, __float_as_uint(__expf(leaky(a.w + b.w) - m.w)));
}

// ---------------- aggregation: one (head,chalf) slab per block, XCD-pinned ----------------
// 32-bit buffer addressing: gather voffset = (src << 7) + ld*4 (one v_lshl_add_u32),
// pk streamed via dwordx2 buffer loads with imm offsets.
__global__ __launch_bounds__(256) void aggregate_v6(const unsigned short* __restrict__ xh_bf,
                                                    const uint2* __restrict__ pk,
                                                    const int* __restrict__ row_off,
                                                    unsigned short* __restrict__ hout,
                                                    int N, int Npad, int M) {
    int i = blockIdx.x;
    int slab = i & 7;
    int h = slab >> 1;
    int t = threadIdx.x;
    int n = (i >> 3) * 8 + ((t >> 6) << 1) + ((t >> 5) & 1);
    if (n >= N) return;
    int ld = t & 31;
    int beg = row_off[n], end = row_off[n + 1];

    i32x4 rx = make_rsrc(xh_bf + (size_t)slab * Npad * 64, (unsigned int)Npad * 128u);
    i32x4 rp = make_rsrc(pk + (size_t)h * M, (unsigned int)M * 8u);
    int ld4 = ld << 2;

    float acc0 = 0.f, acc1 = 0.f, acc2 = 0.f, acc3 = 0.f, den0 = 0.f, den1 = 0.f;
    int e = beg;
    int vo = beg << 3;
    for (; e + 3 < end; e += 4, vo += 32) {
        i32x2 p0 = amd_buf_load_i32x2(rp, vo, 0, 0);
        i32x2 p1 = amd_buf_load_i32x2(rp, vo + 8, 0, 0);
        i32x2 p2 = amd_buf_load_i32x2(rp, vo + 16, 0, 0);
        i32x2 p3 = amd_buf_load_i32x2(rp, vo + 24, 0, 0);
        unsigned int v0 = (unsigned int)amd_buf_load_i32(rx, (p0.x << 7) + ld4, 0, 0);
        unsigned int v1 = (unsigned int)amd_buf_load_i32(rx, (p1.x << 7) + ld4, 0, 0);
        unsigned int v2 = (unsigned int)amd_buf_load_i32(rx, (p2.x << 7) + ld4, 0, 0);
        unsigned int v3 = (unsigned int)amd_buf_load_i32(rx, (p3.x << 7) + ld4, 0, 0);
        float w0 = __uint_as_float((unsigned int)p0.y);
        float w1 = __uint_as_float((unsigned int)p1.y);
        float w2 = __uint_as_float((unsigned int)p2.y);
        float w3 = __uint_as_float((unsigned int)p3.y);
        den0 += w0 + w2; den1 += w1 + w3;
        acc0 += w0 * bflo(v0); acc1 += w0 * bfhi(v0);
        acc2 += w1 * bflo(v1); acc3 += w1 * bfhi(v1);
        acc0 += w2 * bflo(v2); acc1 += w2 * bfhi(v2);
        acc2 += w3 * bflo(v3); acc3 += w3 * bfhi(v3);
    }
    for (; e < end; ++e, vo += 8) {
        i32x2 p0 = amd_buf_load_i32x2(rp, vo, 0, 0);
        unsigned int v0 = (unsigned int)amd_buf_load_i32(rx, (p0.x << 7) + ld4, 0, 0);
        float w0 = __uint_as_float((unsigned int)p0.y);
        den0 += w0;
        acc0 += w0 * bflo(v0); acc1 += w0 * bfhi(v0);
    }
    float inv = 1.f / (den0 + den1);
    unsigned int o = f2bf_bits((acc0 + acc2) * inv) | (f2bf_bits((acc1 + acc3) * inv) << 16);
    ((unsigned int*)hout)[((size_t)slab * Npad + n) * 32 + ld] = o;
}

// ---------------- head mean + bias -> bf16 feats ----------------
__global__ void combine_kernel(const unsigned short* __restrict__ hout,
                               const float* __restrict__ bias,
                               unsigned short* __restrict__ featsbf, int N, int Npad) {
    int i = blockIdx.x * blockDim.x + threadIdx.x;   // dword index over [N][64]
    if (i >= N * 64) return;
    int n = i >> 6, c2 = i & 63;
    int chalf = c2 >> 5, ld = c2 & 31;
    const unsigned int* hp = (const unsigned int*)hout;
    float lo = 0.f, hi = 0.f;
    #pragma unroll
    for (int h = 0; h < 4; ++h) {
        unsigned int v = hp[((size_t)(h * 2 + chalf) * Npad + n) * 32 + ld];
        lo += bflo(v); hi += bfhi(v);
    }
    lo = 0.25f * lo + bias[c2 * 2];
    hi = 0.25f * hi + bias[c2 * 2 + 1];
    ((unsigned int*)featsbf)[(size_t)n * 64 + c2] = f2bf_bits(lo) | (f2bf_bits(hi) << 16);
}

// ---------------- pairwise scorer (bf16 feats) ----------------
__global__ __launch_bounds__(256) void pair_kernel(const unsigned short* __restrict__ featsbf,
                                                   const float* __restrict__ x,
                                                   const int* __restrict__ idx, int P,
                                                   const float* __restrict__ fc_w,
                                                   const float* __restrict__ fc_b,
                                                   float* __restrict__ out) {
    int p = blockIdx.x * 4 + (threadIdx.x >> 6);
    int l = threadIdx.x & 63;
    if (p >= P) return;
    int i0 = idx[p], i1 = idx[P + p];
    unsigned int a = ((const unsigned int*)featsbf)[(size_t)i0 * 64 + l];
    unsigned int b = ((const unsigned int*)featsbf)[(size_t)i1 * 64 + l];
    float s = bflo(a) * bflo(b) + bfhi(a) * bfhi(b);
    #pragma unroll
    for (int off = 32; off >= 1; off >>= 1) s += __shfl_xor(s, off);
    if (l == 0) {
        float dx = x[(size_t)i0 * 130] - x[(size_t)i1 * 130];
        float dy = x[(size_t)i0 * 130 + 1] - x[(size_t)i1 * 130 + 1];
        float pe = dx * dx + dy * dy;
        out[p] = fc_w[0] * s + fc_w[1] * pe + fc_b[0];
    }
}

extern "C" void kernel_launch(void* const* d_in, const int* in_sizes, int n_in,
                              void* d_out, int out_size, void* d_ws, size_t ws_size,
                              hipStream_t stream) {
    const float* x   = (const float*)d_in[0];
    const int*   ei  = (const int*)d_in[1];
    const int*   idx = (const int*)d_in[2];
    const float* W1  = (const float*)d_in[3];
    const float* as1 = (const float*)d_in[4];
    const float* ad1 = (const float*)d_in[5];
    const float* b1  = (const float*)d_in[6];
    const float* W2  = (const float*)d_in[7];
    const float* as2 = (const float*)d_in[8];
    const float* ad2 = (const float*)d_in[9];
    const float* b2  = (const float*)d_in[10];
    const float* fcw = (const float*)d_in[11];
    const float* fcb = (const float*)d_in[12];
    float* out = (float*)d_out;

    const int N = in_sizes[0] / 130;
    const int E = in_sizes[1] / 2;
    const int P = in_sizes[2] / 2;
    const int M = E + N;
    const int Npad = (N + 127) & ~127;

    char* ws = (char*)d_ws;
    size_t off = 0;
    auto alloc = [&](size_t bytes) -> void* {
        void* p = ws + off;
        off += (bytes + 255) & ~(size_t)255;
        return p;
    };
    unsigned short* xh_bf   = (unsigned short*)alloc((size_t)Npad * FOUT * 2);
    unsigned short* hout    = (unsigned short*)alloc((size_t)Npad * FOUT * 2);
    unsigned short* xA      = (unsigned short*)alloc((size_t)Npad * C * 2);
    unsigned short* featsbf = (unsigned short*)alloc((size_t)Npad * C * 2);
    unsigned short* Wt1     = (unsigned short*)alloc((size_t)128 * FOUT * 2);
    unsigned short* Wt2     = (unsigned short*)alloc((size_t)128 * FOUT * 2);
    float*          alpha_s = (float*)alloc((size_t)N * H * 4);
    float*          alpha_d = (float*)alloc((size_t)N * H * 4);
    float*          mbuf    = (float*)alloc((size_t)N * H * 4);
    uint2*          pk      = (uint2*)alloc((size_t)M * H * 8);
    int*            row_off = (int*)alloc((size_t)(N + 1) * 4);
    int*            cursor  = (int*)alloc((size_t)N * 4);
    int*            counts  = (int*)alloc((size_t)N * 4);
    int*            csr_src = (int*)alloc((size_t)M * 4);
    int*            csr_dst = (int*)alloc((size_t)M * 4);

    // CSR by dst (shared across both layers)
    zero_i32<<<(N + 255) / 256, 256, 0, stream>>>(counts, N);
    hist_kernel<<<(M + 255) / 256, 256, 0, stream>>>(ei, E, N, counts);
    scan_kernel<<<1, 256, 0, stream>>>(counts, row_off, cursor, N);
    scatter_kernel<<<(M + 255) / 256, 256, 0, stream>>>(ei, E, N, cursor, csr_src, csr_dst);

    // input conversions
    convert_x<<<(Npad * (C / 4) + 255) / 256, 256, 0, stream>>>(x, xA, featsbf, N, Npad);
    convert_w<<<(128 * FOUT + 255) / 256, 256, 0, stream>>>(W1, W2, Wt1, Wt2);

    dim3 ggrid(H, Npad / 128);
    int aggGrid = ((N + 7) / 8) * 8;
    int cmbGrid = (N * 64 + 255) / 256;

    // layer 1
    gemm_mfma<<<ggrid, 256, 0, stream>>>(xA, Wt1, as1, ad1, xh_bf, alpha_s, alpha_d, N, Npad);
    max_kernel<<<(N + 3) / 4, 256, 0, stream>>>((const float4*)alpha_s, (const float4*)alpha_d,
                                                row_off, csr_src, (float4*)mbuf, N);
    weight_kernel<<<(M + 255) / 256, 256, 0, stream>>>(csr_src, csr_dst, M, (const float4*)alpha_s,
                                                       (const float4*)alpha_d, (const float4*)mbuf,
                                                       pk);
    aggregate_v6<<<aggGrid, 256, 0, stream>>>(xh_bf, pk, row_off, hout, N, Npad, M);
    combine_kernel<<<cmbGrid, 256, 0, stream>>>(hout, b1, featsbf, N, Npad);

    // layer 2
    gemm_mfma<<<ggrid, 256, 0, stream>>>(featsbf, Wt2, as2, ad2, xh_bf, alpha_s, alpha_d, N, Npad);
    max_kernel<<<(N + 3) / 4, 256, 0, stream>>>((const float4*)alpha_s, (const float4*)alpha_d,
                                                row_off, csr_src, (float4*)mbuf, N);
    weight_kernel<<<(M + 255) / 256, 256, 0, stream>>>(csr_src, csr_dst, M, (const float4*)alpha_s,
                                                       (const float4*)alpha_d, (const float4*)mbuf,
                                                       pk);
    aggregate_v6<<<aggGrid, 256, 0, stream>>>(xh_bf, pk, row_off, hout, N, Npad, M);
    combine_kernel<<<cmbGrid, 256, 0, stream>>>(hout, b2, featsbf, N, Npad);

    // pairwise output
    pair_kernel<<<(P + 3) / 4, 256, 0, stream>>>(featsbf, x, idx, P, fcw, fcb, out);
}